// Round 6
// baseline (366.035 us; speedup 1.0000x reference)
//
#include <hip/hip_runtime.h>
#include <hip/hip_bf16.h>
#include <math.h>
#include <utility>

typedef __hip_bfloat16 bf16;
typedef __attribute__((ext_vector_type(8))) short bf16x8;   // 8 bf16 = 4 VGPRs (MFMA A/B frag)
typedef __attribute__((ext_vector_type(4))) short bf16x4;   // 4 bf16 = 8B packed store
typedef __attribute__((ext_vector_type(4))) float floatx4;  // MFMA C/D frag

// async global->LDS, 16B per lane. LDS dest = wave-uniform base + lane*16.
__device__ __forceinline__ void async_copy16(const bf16* g, bf16* l) {
    __builtin_amdgcn_global_load_lds(
        (__attribute__((address_space(1))) void*)(void*)g,
        (__attribute__((address_space(3))) void*)(void*)l,
        16, 0, 0);
}

// ---------------- cast x: fp32 -> bf16, float4-vectorized ----------------
__global__ __launch_bounds__(256) void cast_f32_bf16(const float* __restrict__ in,
                                                     bf16* __restrict__ out, int n4) {
    int i = blockIdx.x * 256 + threadIdx.x;
    if (i >= n4) return;
    float4 v = ((const float4*)in)[i];
    union { ushort4 u; bf16 b[4]; } o;
    o.b[0] = __float2bfloat16(v.x);
    o.b[1] = __float2bfloat16(v.y);
    o.b[2] = __float2bfloat16(v.z);
    o.b[3] = __float2bfloat16(v.w);
    ((ushort4*)out)[i] = o.u;
}

// ------- cast + transpose: in fp32 [K][N] -> out bf16 [N][K] (LDS tile) -------
__global__ __launch_bounds__(256) void cast_transpose(const float* __restrict__ in,
                                                      bf16* __restrict__ out, int K, int N) {
    __shared__ float tile[32][33];
    int nb = blockIdx.x * 32, kb = blockIdx.y * 32;
    for (int j = threadIdx.y; j < 32; j += 8)
        tile[j][threadIdx.x] = in[(size_t)(kb + j) * N + nb + threadIdx.x];
    __syncthreads();
    for (int j = threadIdx.y; j < 32; j += 8)
        out[(size_t)(nb + j) * K + kb + threadIdx.x] = __float2bfloat16(tile[threadIdx.x][j]);
}

// ---------------- m97-style bf16 GEMM, XOR-swizzled LDS ----------------
__global__ __launch_bounds__(256) void gemm_bt(const bf16* __restrict__ A,
                                               const bf16* __restrict__ Bt,
                                               bf16* __restrict__ Cout,
                                               int M, int N, int K) {
    __shared__ bf16 As[128 * 32];
    __shared__ bf16 Bs[128 * 32];
    const int tid = threadIdx.x;
    const int wave = tid >> 6, lane = tid & 63;
    const int c = lane & 15, quad = lane >> 4;
    const int wm = wave >> 1, wn = wave & 1;
    const int mBase = blockIdx.y * 128, nBase = blockIdx.x * 128;

    const int sRow = lane >> 2;
    const int sCol = ((lane & 3) ^ ((lane >> 3) & 3)) << 3;   // swizzled source chunk
    const int rdOff = (quad ^ ((c >> 1) & 3)) << 3;           // swizzled read offset
    const bf16* gA = A + (size_t)(mBase + wave * 32 + sRow) * K + sCol;
    const bf16* gB = Bt + (size_t)(nBase + wave * 32 + sRow) * K + sCol;
    bf16* lA = As + wave * 1024;
    bf16* lB = Bs + wave * 1024;

    floatx4 acc[4][4];
#pragma unroll
    for (int mt = 0; mt < 4; mt++)
#pragma unroll
        for (int nt = 0; nt < 4; nt++) acc[mt][nt] = (floatx4){0.f, 0.f, 0.f, 0.f};

    for (int k0 = 0; k0 < K; k0 += 32) {
        async_copy16(gA + k0, lA);
        async_copy16(gA + k0 + 16 * K, lA + 512);
        async_copy16(gB + k0, lB);
        async_copy16(gB + k0 + 16 * K, lB + 512);
        __syncthreads();
        bf16x8 af[4], bfr[4];
#pragma unroll
        for (int mt = 0; mt < 4; mt++)
            af[mt] = *(const bf16x8*)(As + (wm * 64 + mt * 16 + c) * 32 + rdOff);
#pragma unroll
        for (int nt = 0; nt < 4; nt++)
            bfr[nt] = *(const bf16x8*)(Bs + (wn * 64 + nt * 16 + c) * 32 + rdOff);
#pragma unroll
        for (int mt = 0; mt < 4; mt++)
#pragma unroll
            for (int nt = 0; nt < 4; nt++)
                acc[mt][nt] = __builtin_amdgcn_mfma_f32_16x16x32_bf16(af[mt], bfr[nt],
                                                                      acc[mt][nt], 0, 0, 0);
        __syncthreads();
    }
#pragma unroll
    for (int mt = 0; mt < 4; mt++)
#pragma unroll
        for (int nt = 0; nt < 4; nt++)
#pragma unroll
            for (int r = 0; r < 4; r++) {
                int row = mBase + wm * 64 + mt * 16 + quad * 4 + r;
                int col = nBase + wn * 64 + nt * 16 + c;
                Cout[(size_t)row * N + col] = __float2bfloat16(acc[mt][nt][r]);
            }
}

// ---------------- split-K GEMM (K halves), fp32 atomic accumulate ----------------
// grid.z selects K range [z*1024, z*1024+1024). Cout must be zero-initialized.
// Two commutative fp32 adds per element -> deterministic result.
__global__ __launch_bounds__(256) void gemm_bt_sk(const bf16* __restrict__ A,
                                                  const bf16* __restrict__ Bt,
                                                  float* __restrict__ Cout,
                                                  int M, int N, int K) {
    __shared__ bf16 As[128 * 32];
    __shared__ bf16 Bs[128 * 32];
    const int tid = threadIdx.x;
    const int wave = tid >> 6, lane = tid & 63;
    const int c = lane & 15, quad = lane >> 4;
    const int wm = wave >> 1, wn = wave & 1;
    const int mBase = blockIdx.y * 128, nBase = blockIdx.x * 128;
    const int kz = blockIdx.z * 1024;

    const int sRow = lane >> 2;
    const int sCol = ((lane & 3) ^ ((lane >> 3) & 3)) << 3;
    const int rdOff = (quad ^ ((c >> 1) & 3)) << 3;
    const bf16* gA = A + (size_t)(mBase + wave * 32 + sRow) * K + sCol;
    const bf16* gB = Bt + (size_t)(nBase + wave * 32 + sRow) * K + sCol;
    bf16* lA = As + wave * 1024;
    bf16* lB = Bs + wave * 1024;

    floatx4 acc[4][4];
#pragma unroll
    for (int mt = 0; mt < 4; mt++)
#pragma unroll
        for (int nt = 0; nt < 4; nt++) acc[mt][nt] = (floatx4){0.f, 0.f, 0.f, 0.f};

    for (int k0 = kz; k0 < kz + 1024; k0 += 32) {
        async_copy16(gA + k0, lA);
        async_copy16(gA + k0 + 16 * K, lA + 512);
        async_copy16(gB + k0, lB);
        async_copy16(gB + k0 + 16 * K, lB + 512);
        __syncthreads();
        bf16x8 af[4], bfr[4];
#pragma unroll
        for (int mt = 0; mt < 4; mt++)
            af[mt] = *(const bf16x8*)(As + (wm * 64 + mt * 16 + c) * 32 + rdOff);
#pragma unroll
        for (int nt = 0; nt < 4; nt++)
            bfr[nt] = *(const bf16x8*)(Bs + (wn * 64 + nt * 16 + c) * 32 + rdOff);
#pragma unroll
        for (int mt = 0; mt < 4; mt++)
#pragma unroll
            for (int nt = 0; nt < 4; nt++)
                acc[mt][nt] = __builtin_amdgcn_mfma_f32_16x16x32_bf16(af[mt], bfr[nt],
                                                                      acc[mt][nt], 0, 0, 0);
        __syncthreads();
    }
#pragma unroll
    for (int mt = 0; mt < 4; mt++)
#pragma unroll
        for (int nt = 0; nt < 4; nt++)
#pragma unroll
            for (int r = 0; r < 4; r++) {
                int row = mBase + wm * 64 + mt * 16 + quad * 4 + r;
                int col = nBase + wn * 64 + nt * 16 + c;
                unsafeAtomicAdd(&Cout[(size_t)row * N + col], acc[mt][nt][r]);
            }
}

// ---------------- RoPE (K only), in place on bf16 ----------------
__global__ __launch_bounds__(256) void rope_kernel(bf16* __restrict__ X, int heads, int rowStride) {
    int idx = blockIdx.x * 256 + threadIdx.x;
    int d = idx & 63;
    int h = (idx >> 6) % heads;
    int row = idx / (heads * 64);
    int t = row & 2047;
    float theta = exp2f(-(float)d * 0.20762050593045827f);  // 10000^(-d/64)
    float ang = (float)t * theta;
    float sv, cv;
    __sincosf(ang, &sv, &cv);
    bf16* p = X + (size_t)row * rowStride + h * 128 + d;
    float x1 = __bfloat162float(p[0]);
    float x2 = __bfloat162float(p[64]);
    p[0]  = __float2bfloat16(x1 * cv - x2 * sv);
    p[64] = __float2bfloat16(x2 * cv + x1 * sv);
}

// ------- V transpose: QKV V-block [t][d] -> Vtg [b*4+kvh][d=128][t=2048] -------
__global__ __launch_bounds__(256) void vtrans(const bf16* __restrict__ QKV,
                                              bf16* __restrict__ Vtg) {
    __shared__ bf16 tile[32][34];
    const int bh = blockIdx.z;
    const int b = bh >> 2, kvh = bh & 3;
    const int t0 = blockIdx.x * 32, d0 = blockIdx.y * 32;
    const bf16* src = QKV + (size_t)b * 2048 * 3072 + 2560 + kvh * 128;
    for (int j = threadIdx.y; j < 32; j += 8)
        tile[j][threadIdx.x] = src[(size_t)(t0 + j) * 3072 + d0 + threadIdx.x];
    __syncthreads();
    bf16* dst = Vtg + (size_t)bh * 128 * 2048;
    for (int j = threadIdx.y; j < 32; j += 8)
        dst[(size_t)(d0 + j) * 2048 + t0 + threadIdx.x] = tile[threadIdx.x][j];
}

// ---------------- flash attention v6: S^T formulation, split-kv partials ----------------
// QK^T computed TRANSPOSED (mfma(kf,qf) -> D[m=key][n=q]): a lane then holds 4
// CONSECUTIVE keys for one q=c -> P writes to LDS are packed ds_write_b64, lrow
// is a single scalar per lane, and PV runs as O^T = V^T x P (P read as b128
// B-frag from an XOR-swizzled [q][64] layout). Output O^T stores as packed b64.
// Split-kv partials as in v5 (linear merge, no online max). LDS = 40960 B
// exactly -> 4 blocks/CU.
__global__ __launch_bounds__(256, 4) void flash_attn6(const bf16* __restrict__ QKV,
                                                      const bf16* __restrict__ Vtg,
                                                      bf16* __restrict__ Slot0,
                                                      bf16* __restrict__ Slot1,
                                                      float* __restrict__ Ls) {
    const int T = 2048, STR = 3072;
    __shared__ bf16 Ks[4 * 64 * 32];      // 16 KB  [d-chunk][key 64][32]
    __shared__ bf16 Vs[2 * 128 * 32];     // 16 KB  [key-chunk][d 128][32]
    __shared__ bf16 Pl[4][16 * 64];       // 8 KB   per-wave P, [q][key] XOR-swizzled
    const int b = blockIdx.z, h = blockIdx.y;
    const int pj = blockIdx.x >> 1, s = blockIdx.x & 1;
    const int kvh = h >> 2;
    const int tid = threadIdx.x, wave = tid >> 6, lane = tid & 63;
    const int c = lane & 15, quad = lane >> 4;
    const float C2 = 0.12751541717525597f;  // (1/sqrt(128)) * log2(e), folded into Q

    const bf16* Kg = QKV + (size_t)b * T * STR + 2048 + kvh * 128;
    const bf16* Vg = Vtg + (size_t)(b * 4 + kvh) * 128 * 2048;
    const int srow = tid >> 2;
    const int xcol = ((tid & 3) ^ ((tid >> 3) & 3)) << 3;   // swizzled staging chunk
    const int koff = (quad ^ ((c >> 1) & 3)) << 3;          // swizzled read offset
    bf16* PlW = &Pl[wave][0];
    // P write address: key chunk (nt*2 + quad/2) xor (c&7), half-chunk quad&1
    const int pwBase = c * 64 + (quad & 1) * 4;
    const int qa = 31 - pj;

    auto run_part = [&](int qtile, int ktlo, int kthi, bf16* slot, int lsSlot) {
        const int q0 = qtile * 64;
        // Q frags + RoPE + scale fold, in-register
        bf16x8 qf[4];
        {
            const bf16* qp = QKV + ((size_t)b * T + q0 + wave * 16 + c) * STR + h * 128 + quad * 8;
#pragma unroll
            for (int ks = 0; ks < 4; ks++) qf[ks] = *(const bf16x8*)(qp + ks * 32);
            const float t = (float)(q0 + wave * 16 + c);
#pragma unroll
            for (int ks = 0; ks < 2; ks++)
#pragma unroll
                for (int j = 0; j < 8; j++) {
                    int d = ks * 32 + quad * 8 + j;
                    float theta = exp2f((float)d * -0.20762050593045827f);
                    float sv, cv;
                    __sincosf(t * theta, &sv, &cv);
                    float lo = __bfloat162float(((const bf16*)&qf[ks])[j]);
                    float hi = __bfloat162float(((const bf16*)&qf[ks + 2])[j]);
                    ((bf16*)&qf[ks])[j]     = __float2bfloat16((lo * cv - hi * sv) * C2);
                    ((bf16*)&qf[ks + 2])[j] = __float2bfloat16((hi * cv + lo * sv) * C2);
                }
        }
        floatx4 accO[8];
#pragma unroll
        for (int nt = 0; nt < 8; nt++) accO[nt] = (floatx4){0.f, 0.f, 0.f, 0.f};
        float lrow = 0.f;

        auto tile = [&](int kt0, auto DIAGC) {
            constexpr bool DIAG = decltype(DIAGC)::value;
#pragma unroll
            for (int it = 0; it < 4; it++) {
                async_copy16(Kg + (size_t)(kt0 + srow) * STR + it * 32 + xcol,
                             Ks + it * 2048 + wave * 512);
                async_copy16(Vg + (size_t)((it & 1) * 64 + srow) * 2048 + kt0 + (it >> 1) * 32 + xcol,
                             Vs + it * 2048 + wave * 512);
            }
            __syncthreads();
            // S^T[64 key][16 q]: mfma(A=K frag, B=Q frag)
            floatx4 sf[4];
#pragma unroll
            for (int nt = 0; nt < 4; nt++) sf[nt] = (floatx4){0.f, 0.f, 0.f, 0.f};
#pragma unroll
            for (int ks = 0; ks < 4; ks++)
#pragma unroll
                for (int nt = 0; nt < 4; nt++) {
                    bf16x8 kf = *(const bf16x8*)(Ks + ks * 2048 + (nt * 16 + c) * 32 + koff);
                    sf[nt] = __builtin_amdgcn_mfma_f32_16x16x32_bf16(kf, qf[ks], sf[nt], 0, 0, 0);
                }
            // exp; lane owns keys nt*16+quad*4+r for q = c. Packed b64 P writes.
#pragma unroll
            for (int nt = 0; nt < 4; nt++) {
                bf16x4 pk;
#pragma unroll
                for (int r = 0; r < 4; r++) {
                    float p = exp2f(sf[nt][r]);
                    if (DIAG)
                        if (nt * 16 + quad * 4 + r > wave * 16 + c) p = 0.f;
                    lrow += p;
                    ((bf16*)&pk)[r] = __float2bfloat16(p);
                }
                *(bf16x4*)(PlW + pwBase + (((nt * 2 + (quad >> 1)) ^ (c & 7)) << 3)) = pk;
            }
            // O^T += V^T x P: A = V^T frag (m=d), B = P frag (n=q)
#pragma unroll
            for (int kc = 0; kc < 2; kc++) {
                bf16x8 pf = *(const bf16x8*)(PlW + c * 64 + ((((kc << 2) + quad) ^ (c & 7)) << 3));
#pragma unroll
                for (int nt = 0; nt < 8; nt++) {
                    bf16x8 vf = *(const bf16x8*)(Vs + kc * 4096 + (nt * 16 + c) * 32 + koff);
                    accO[nt] = __builtin_amdgcn_mfma_f32_16x16x32_bf16(vf, pf, accO[nt], 0, 0, 0);
                }
            }
            __syncthreads();
        };

        const int ndiag = (kthi > qtile) ? qtile : kthi;   // non-diag upper bound
        for (int kt = ktlo; kt < ndiag; kt++)
            tile(kt * 64, std::integral_constant<bool, false>{});
        if (kthi > qtile)
            tile(qtile * 64, std::integral_constant<bool, true>{});

        // row-sum: lane holds partial for q=c; reduce across the 4 quads
        float sred = lrow;
        sred += __shfl_xor(sred, 16);
        sred += __shfl_xor(sred, 32);
        if (quad == 0)
            Ls[(size_t)lsSlot * 65536 + ((size_t)(b * 16 + h) * 32 + qtile) * 64
               + wave * 16 + c] = sred;
        // O^T store: accO[nt][r] -> (q = q0+wave*16+c, d = nt*16+quad*4+r), packed b64
        bf16* orow = slot + (size_t)(b * T + q0 + wave * 16 + c) * 2048 + h * 128 + quad * 4;
#pragma unroll
        for (int nt = 0; nt < 8; nt++) {
            bf16x4 o;
#pragma unroll
            for (int r = 0; r < 4; r++) ((bf16*)&o)[r] = __float2bfloat16(accO[nt][r]);
            *(bf16x4*)(orow + nt * 16) = o;
        }
    };

    if (s == 0) {
        run_part(qa, 0, 17, Slot0, 0);
    } else {
        run_part(qa, 17, 32 - pj, Slot1, 1);   // empty for pj==15 -> writes zeros
        run_part(pj, 0, pj + 1, Slot0, 0);
    }
}

// ---------------- merge partials: AO = (Slot0 + Slot1) / (l0 + l1) ----------------
__global__ __launch_bounds__(256) void attn_merge(bf16* __restrict__ AO,
                                                  const bf16* __restrict__ P1,
                                                  const float* __restrict__ Ls) {
    int i = blockIdx.x * 256 + threadIdx.x;   // 1,048,576 threads, 8 cols each
    int row = i >> 8;                         // 0..4095
    int cg = (i & 255) << 3;                  // col 0..2040 step 8
    int b = row >> 11, t = row & 2047;
    int qtile = t >> 6;
    int h = cg >> 7;
    size_t off = (size_t)row * 2048 + cg;
    size_t li = ((size_t)(b * 16 + h) * 32 + qtile) * 64 + (t & 63);
    bf16x8 a0 = *(const bf16x8*)(AO + off);
    float l = Ls[li];
    float acc[8];
#pragma unroll
    for (int j = 0; j < 8; j++) acc[j] = __bfloat162float(((const bf16*)&a0)[j]);
    if (qtile >= 16) {   // q-tiles 16..31 have a second partial
        bf16x8 a1 = *(const bf16x8*)(P1 + off);
        l += Ls[65536 + li];
#pragma unroll
        for (int j = 0; j < 8; j++) acc[j] += __bfloat162float(((const bf16*)&a1)[j]);
    }
    float inv = 1.0f / l;
    bf16x8 o;
#pragma unroll
    for (int j = 0; j < 8; j++) ((bf16*)&o)[j] = __float2bfloat16(acc[j] * inv);
    *(bf16x8*)(AO + off) = o;
}

extern "C" void kernel_launch(void* const* d_in, const int* in_sizes, int n_in,
                              void* d_out, int out_size, void* d_ws, size_t ws_size,
                              hipStream_t stream) {
    const float* x  = (const float*)d_in[0];
    const float* Wq = (const float*)d_in[1];
    const float* Wk = (const float*)d_in[2];
    const float* Wv = (const float*)d_in[3];
    const float* Wo = (const float*)d_in[4];

    char* ws = (char*)d_ws;
    bf16* xb   = (bf16*)(ws);                 // [4096][2048] (dead after QKV GEMM)
    bf16* Vtg  = (bf16*)(ws);                 // reuses xb: [8][128][2048] = 4 MB
    bf16* Slt1 = (bf16*)(ws + 4194304);       // 16.78 MB, overlays dead xb-tail + Wt
    float* Ls  = (float*)(ws + 20971520);     // 0.5 MB lsum[2][b][h][qtile][64]
    bf16* Wt   = (bf16*)(ws + 16777216);      // [3072][2048] Wq|Wk|Wv (dead before flash)
    bf16* Wot  = (bf16*)(ws + 29360128);      // [2048][2048] (live until out-proj)
    bf16* QKV  = (bf16*)(ws + 37748736);      // [4096][3072]
    bf16* AO   = (bf16*)(ws + 62914560);      // [4096][2048] = partial Slot0, merged in place

    // zero d_out for split-K atomic accumulation (graph-capture safe)
    hipMemsetAsync(d_out, 0, (size_t)out_size * 4, stream);

    cast_f32_bf16<<<8192, 256, 0, stream>>>(x, xb, 2097152);
    cast_transpose<<<dim3(64, 64), dim3(32, 8), 0, stream>>>(Wq, Wt, 2048, 2048);
    cast_transpose<<<dim3(16, 64), dim3(32, 8), 0, stream>>>(Wk, Wt + 2048 * 2048, 2048, 512);
    cast_transpose<<<dim3(16, 64), dim3(32, 8), 0, stream>>>(Wv, Wt + 2560 * 2048, 2048, 512);
    cast_transpose<<<dim3(64, 64), dim3(32, 8), 0, stream>>>(Wo, Wot, 2048, 2048);

    // QKV projection (consumes xb, Wt — both dead afterwards)
    gemm_bt<<<dim3(24, 32), 256, 0, stream>>>(xb, Wt, QKV, 4096, 3072, 2048);

    // RoPE on K only (Q-RoPE fused into flash_attn6)
    rope_kernel<<<4096, 256, 0, stream>>>(QKV + 2048, 4, 3072);

    // V transpose (into Vtg at ws base)
    vtrans<<<dim3(64, 4, 8), dim3(32, 8), 0, stream>>>(QKV, Vtg);

    // split-kv flash attention: 16 pairs x 2 splits x 16 heads x 2 batch = 1024 uniform blocks
    flash_attn6<<<dim3(32, 16, 2), 256, 0, stream>>>(QKV, Vtg, AO, Slt1, Ls);

    // merge partials -> AO (in place)
    attn_merge<<<4096, 256, 0, stream>>>(AO, Slt1, Ls);

    // output projection, split-K x2 -> fp32 atomic accumulate into d_out
    gemm_bt_sk<<<dim3(16, 32, 2), 256, 0, stream>>>(AO, Wot, (float*)d_out, 4096, 2048, 2048);
}